// Round 20
// baseline (254.153 us; speedup 1.0000x reference)
//
#include <hip/hip_runtime.h>
#include <hip/hip_fp16.h>
#include <stdint.h>

typedef __attribute__((ext_vector_type(4))) int int32x4;
typedef __attribute__((ext_vector_type(4))) float float32x4;

#define TOKENS 8192
#define IN_F   4096
#define OUT_F  4096
#define BM 256
#define BN 256
#define BK 128              // int8 per K-tile = 128 B rows
#define NT (IN_F / BK)      // 32 K-tiles
#define ESTR 260            // epilogue LDS row stride (f32): 2-way bank alias = free

#define AS1 __attribute__((address_space(1)))
#define AS3 __attribute__((address_space(3)))

// ------- fused pack: int32->int8 for x and w, plus bias tuple-output -------
__global__ __launch_bounds__(256)
void pack_all_kernel(const int* __restrict__ x32, const int* __restrict__ w32,
                     const float* __restrict__ bias,
                     uint32_t* __restrict__ x8, uint32_t* __restrict__ w8,
                     float* __restrict__ bias_out)
{
    const int gid = blockIdx.x * 256 + threadIdx.x;
    if (gid < OUT_F / 4) {
        float32x4 b4 = __builtin_nontemporal_load((const float32x4*)bias + gid);
        __builtin_nontemporal_store(b4, (float32x4*)bias_out + gid);
    }

    const int nx4 = TOKENS * IN_F / 4;
    const int nw4 = OUT_F * IN_F / 4;
    for (int i = gid; i < nx4 + nw4; i += gridDim.x * 256) {
        const int* s; uint32_t* d; int j;
        if (i < nx4) { s = x32; d = x8; j = i; }
        else         { s = w32; d = w8; j = i - nx4; }
        int32x4 v = __builtin_nontemporal_load((const int32x4*)s + j);
        d[j] = (uint32_t)(v[0] & 0xff) | ((uint32_t)(v[1] & 0xff) << 8) |
               ((uint32_t)(v[2] & 0xff) << 16) | ((uint32_t)v[3] << 24);
    }
}

// ---- 256x256 i8 GEMM: 4 FAT waves (128x128 wave-tile) --------------------
// 256 threads = 4 waves (wqm x wqn quadrants). Per wave per tile: 32
// ds_read_b128 (16 A + 16 B) feeding 128 MFMA -> LDS frag-read bytes drop
// 192 KB -> 128 KB per tile per CU (the measured CU-shared LDS-pipe term).
// acc = 8x8 16x16-frags = 256 VGPR -> 1 wave/SIMD (launch_bounds(256,1)).
// Schedule = r12-verified: reads -> stage t+1 -> MFMA -> vmcnt(0) -> barrier.
__global__ __launch_bounds__(256, 1)
void w8a8_gemm_kernel(const int8_t* __restrict__ x,
                      const int8_t* __restrict__ wq,
                      const float* __restrict__ scale,
                      const float* __restrict__ bias,
                      float* __restrict__ out)
{
    __shared__ int8_t smem[131072];            // staging: lA | lB ; epilogue reuse
    int8_t* lA = smem;                         // [buf][half][128][128B] 64 KB
    int8_t* lB = smem + 65536;                 // 64 KB

    const int tid = threadIdx.x;
    const int wv  = tid >> 6;              // 0..3
    const int l   = tid & 63;
    const int wqm = wv >> 1;               // 0..1  (128-row half)
    const int wqn = wv & 1;                // 0..1  (128-col half)

    // XCD-chunked bijective swizzle (r10-proven): 512 blocks = 8 XCDs x (8bn x 8bm)
    const int xc  = blockIdx.x & 7;
    const int idx = blockIdx.x >> 3;
    const int bn  = (xc & 1) * 8 + (idx & 7);    // 0..15
    const int bm  = (xc >> 1) * 8 + (idx >> 3);  // 0..31

    const int8_t* baseA = x + (size_t)bm * BM * IN_F;
    const int8_t* baseB = wq + (size_t)bn * BN * IN_F;

    // staging: T2 swizzle via pre-swizzled global source (rule 21).
    // Per half-tile (16 KB): 4 issues/thread; issue i covers rows wv*32+i*8..+7.
    const int r8   = l >> 3;
    const int swc  = (((l & 7) ^ r8) << 4);
    const int8_t* pA = baseA + (size_t)(wv * 32 + r8) * IN_F + swc;
    const int8_t* pB = baseB + (size_t)(wv * 32 + r8) * IN_F + swc;

    // fragment read addressing (r12-verified)
    const int fr  = l & 15;
    const int xk  = (l & 7) << 4;
    const int cb0 = (l >> 4) << 4;

    int32x4 acc[8][8];                     // 256 VGPR accumulator
#pragma unroll
    for (int mi = 0; mi < 8; ++mi)
#pragma unroll
        for (int ni = 0; ni < 8; ++ni)
            acc[mi][ni] = (int32x4){0, 0, 0, 0};

    int32x4 aF[8], bF[8];                  // one k-half set, reused per ks pass

    auto stage_half = [&](int h4) {        // 4 x global_load_lds (4 KB/wave)
        const int kt_ = h4 >> 2;
        const int wh_ = h4 & 3;            // 0:A0 1:A1 2:B0 3:B1
        const size_t off = (size_t)(wh_ & 1) * (128 * IN_F) + (size_t)kt_ * BK;
        const int8_t* s = ((wh_ < 2) ? pA : pB) + off;
        int8_t* db = ((wh_ < 2) ? lA : lB) + ((kt_ & 1) << 15) + ((wh_ & 1) << 14)
                     + wv * 4096;
#pragma unroll
        for (int i = 0; i < 4; ++i)
            __builtin_amdgcn_global_load_lds(
                (const AS1 void*)(s + (size_t)(i * 8) * IN_F),
                (AS3 void*)(db + i * 1024), 16, 0, 0);
    };
    auto stage_tile = [&](int tt) {
        stage_half(4 * tt + 0); stage_half(4 * tt + 1);
        stage_half(4 * tt + 2); stage_half(4 * tt + 3);
    };

#define LDFR(KS, LABP, LBBP)                                                           \
    do {                                                                               \
        _Pragma("unroll") for (int mi = 0; mi < 8; ++mi)                               \
            aF[mi] = *(const int32x4*)&(LABP)[(wqm << 14) +                            \
                (mi * 16 + fr) * 128 + ((((KS) * 64) + cb0) ^ xk)];                    \
        _Pragma("unroll") for (int ni = 0; ni < 8; ++ni)                               \
            bF[ni] = *(const int32x4*)&(LBBP)[(wqn << 14) +                            \
                (ni * 16 + fr) * 128 + ((((KS) * 64) + cb0) ^ xk)];                    \
    } while (0)

#define MMA64()                                                                        \
    do {                                                                               \
        _Pragma("unroll") for (int mi = 0; mi < 8; ++mi)                               \
        _Pragma("unroll") for (int ni = 0; ni < 8; ++ni)                               \
            acc[mi][ni] = __builtin_amdgcn_mfma_i32_16x16x64_i8(                       \
                aF[mi], bF[ni], acc[mi][ni], 0, 0, 0);                                 \
    } while (0)

    // ---- prologue: tile 0 fully staged ----
    stage_tile(0);
    asm volatile("s_waitcnt vmcnt(0)" ::: "memory");
    __builtin_amdgcn_s_barrier();

    // ---- main loop ----
    for (int t = 0; t < NT; ++t) {
        const int8_t* lAb = lA + ((t & 1) << 15);
        const int8_t* lBb = lB + ((t & 1) << 15);

        LDFR(0, lAb, lBb);                     // 16 ds_read_b128 (ks0)
        if (t + 1 < NT) stage_tile(t + 1);     // 16 gload_lds -> other parity
        MMA64();                               // 64 MFMA (ks0)

        LDFR(1, lAb, lBb);                     // 16 ds_read_b128 (ks1)
        MMA64();                               // 64 MFMA (ks1)

        if (t + 1 < NT) asm volatile("s_waitcnt vmcnt(0)" ::: "memory");
        __builtin_amdgcn_s_barrier();
    }

    // ---- epilogue: LDS-staged coalesced float4 nt stores (32-row chunks) ----
    __syncthreads();
    int* eL = (int*)smem;
    const int c4   = tid & 63;          // float4 col index within 256-col block
    const int rowt = tid >> 6;          // 0..3
    const float32x4 sc4 = ((const float32x4*)scale)[bn * 64 + c4];
    const float32x4 bf4 = ((const float32x4*)bias )[bn * 64 + c4];
    const __half bh[4] = { __float2half(bf4[0]), __float2half(bf4[1]),
                           __float2half(bf4[2]), __float2half(bf4[3]) };
    const int r0 = (l >> 4) << 2;

    for (int c = 0; c < 8; ++c) {              // 8 chunks of 32 output rows
        if (wqm == (c >> 2)) {
            const int mb = (c & 3) * 2;
#pragma unroll
            for (int mi2 = 0; mi2 < 2; ++mi2)
#pragma unroll
                for (int ni = 0; ni < 8; ++ni)
#pragma unroll
                    for (int r = 0; r < 4; ++r)
                        eL[(mi2 * 16 + r0 + r) * ESTR +
                           wqn * 128 + ni * 16 + fr] = acc[mb + mi2][ni][r];
        }
        __syncthreads();
#pragma unroll
        for (int p = 0; p < 8; ++p) {          // 32 rows, 4 per pass
            const int rl = p * 4 + rowt;
            int32x4 v = *(const int32x4*)&eL[rl * ESTR + c4 * 4];
            float32x4 o;
#pragma unroll
            for (int j = 0; j < 4; ++j) {
                __half h = __float2half((float)v[j] * sc4[j]);
                o[j] = __half2float(__hadd(h, bh[j]));
            }
            const size_t rowg = (size_t)(bm * 256 + c * 32 + rl);
            __builtin_nontemporal_store(o, (float32x4*)out + rowg * (OUT_F / 4) + bn * 64 + c4);
        }
        __syncthreads();   // copy-out done before next chunk overwrites
    }
#undef LDFR
#undef MMA64
}

extern "C" void kernel_launch(void* const* d_in, const int* in_sizes, int n_in,
                              void* d_out, int out_size, void* d_ws, size_t ws_size,
                              hipStream_t stream)
{
    const int*   x32   = (const int*)d_in[0];
    const int*   w32   = (const int*)d_in[1];
    const float* scale = (const float*)d_in[2];
    const float* bias  = (const float*)d_in[3];
    float* out = (float*)d_out;

    int8_t* x8 = (int8_t*)d_ws;
    int8_t* w8 = x8 + (size_t)TOKENS * IN_F;

    pack_all_kernel<<<3072, 256, 0, stream>>>(x32, w32, bias, (uint32_t*)x8, (uint32_t*)w8,
                                              out + (size_t)TOKENS * OUT_F);

    w8a8_gemm_kernel<<<512, 256, 0, stream>>>(x8, w8, scale, bias, out);
}